// Round 1
// baseline (2074.178 us; speedup 1.0000x reference)
//
#include <hip/hip_runtime.h>
#include <hip/hip_bf16.h>
#include <stdint.h>

#define H_DIM  2048
#define IM_DIM 1024
#define E_NUM  16
#define TOPK   8
#define IS_DIM 2048
#define SCALE_F 2.5f

#define BM 128
#define BN 128
#define BK 32
#define LDSP 40   // padded LDS row stride (elements); 80B keeps 16B alignment, breaks pow2 banks

typedef __attribute__((ext_vector_type(8))) short   short8;
typedef __attribute__((ext_vector_type(8))) __bf16  bf16x8;
typedef __attribute__((ext_vector_type(4))) float   float4v;
typedef unsigned short ushort_t;

static __device__ __forceinline__ ushort_t f2bf(float x) {
    union { float f; uint32_t u; } v; v.f = x;
    uint32_t r = v.u + 0x7fffu + ((v.u >> 16) & 1u);  // round-to-nearest-even
    return (ushort_t)(r >> 16);
}

// ---------------- cast h (fp32 -> bf16) ----------------
__global__ void cast_h_kernel(const float* __restrict__ h, ushort_t* __restrict__ hb, int n4) {
    int i = blockIdx.x * blockDim.x + threadIdx.x;
    if (i < n4) {
        float4 v = ((const float4*)h)[i];
        ushort4 o;
        o.x = f2bf(v.x); o.y = f2bf(v.y); o.z = f2bf(v.z); o.w = f2bf(v.w);
        ((ushort4*)hb)[i] = o;
    }
}

// ---------------- router: sigmoid + top-8 -> dense comb[T,E] ----------------
__global__ void router_kernel(const float* __restrict__ h, const float* __restrict__ gw,
                              float* __restrict__ comb, int T) {
    int t = blockIdx.x;
    int l = threadIdx.x;
    const float* hr = h + (size_t)t * H_DIM;
    __shared__ float logits[E_NUM];
    for (int e = 0; e < E_NUM; e++) {
        const float* g = gw + e * H_DIM;
        float p = 0.f;
        #pragma unroll 8
        for (int j = l; j < H_DIM; j += 64) p += hr[j] * g[j];
        #pragma unroll
        for (int off = 32; off > 0; off >>= 1) p += __shfl_down(p, off);
        if (l == 0) logits[e] = p;
    }
    __syncthreads();
    if (l == 0) {
        float sig[E_NUM]; bool sel[E_NUM];
        #pragma unroll
        for (int e = 0; e < E_NUM; e++) { sig[e] = 1.f / (1.f + expf(-logits[e])); sel[e] = false; }
        #pragma unroll
        for (int k = 0; k < TOPK; k++) {
            int bi = 0; float bv = -1.f;
            #pragma unroll
            for (int e = 0; e < E_NUM; e++)
                if (!sel[e] && sig[e] > bv) { bv = sig[e]; bi = e; }
            sel[bi] = true;
        }
        float s = 0.f;
        #pragma unroll
        for (int e = 0; e < E_NUM; e++) if (sel[e]) s += sig[e];
        float inv = SCALE_F / (s + 1e-6f);
        #pragma unroll
        for (int e = 0; e < E_NUM; e++)
            comb[(size_t)t * E_NUM + e] = sel[e] ? sig[e] * inv : 0.f;
    }
}

// ---------------- GEMM1: act = rowscale * silu(A@Bg) * (A@Bu), bf16 out ----------------
// A: bf16 [M,K] row-major (lda=K). Bg/Bu: fp32 [K,N] row-major (ldb=N), transpose-staged.
__global__ __launch_bounds__(256)
void gemm1_kernel(const ushort_t* __restrict__ A, int lda,
                  const float* __restrict__ Bg0, const float* __restrict__ Bu0,
                  size_t bSeg, int ldb,
                  ushort_t* __restrict__ C0, size_t cSeg, int ldc,
                  const float* __restrict__ comb, int Kdim)
{
    __shared__ ushort_t Als[BM * LDSP];
    __shared__ ushort_t Bgs[BN * LDSP];
    __shared__ ushort_t Bus[BN * LDSP];

    int z = blockIdx.z;
    const float* Bg = Bg0 + (size_t)z * bSeg;
    const float* Bu = Bu0 + (size_t)z * bSeg;
    ushort_t* C = C0 + (size_t)z * cSeg;

    int t0 = blockIdx.x * BM;
    int n0 = blockIdx.y * BN;
    int tid = threadIdx.x;
    int lane = tid & 63, wid = tid >> 6;
    int wm = (wid & 1) * 64, wn = (wid >> 1) * 64;
    int quad = lane >> 4, l15 = lane & 15;

    float4v accg[4][4], accu[4][4];
    #pragma unroll
    for (int i = 0; i < 4; i++)
        #pragma unroll
        for (int j = 0; j < 4; j++) {
            accg[i][j] = (float4v){0.f, 0.f, 0.f, 0.f};
            accu[i][j] = (float4v){0.f, 0.f, 0.f, 0.f};
        }

    int a_r  = tid >> 2, a_oc = tid & 3;                    // A staging: rows a_r, a_r+64
    int b_ko = (tid >> 4) & 3;                              // B staging k-octet
    int b_n  = 2 * ((tid & 15) + ((tid >> 6) << 4));        // B staging even row

    for (int k0 = 0; k0 < Kdim; k0 += BK) {
        __syncthreads();
        // stage A (bf16 copy)
        {
            const ushort_t* s0 = A + (size_t)(t0 + a_r) * lda + k0 + a_oc * 8;
            *(short8*)&Als[a_r * LDSP + a_oc * 8] = *(const short8*)s0;
            const ushort_t* s1 = A + (size_t)(t0 + a_r + 64) * lda + k0 + a_oc * 8;
            *(short8*)&Als[(a_r + 64) * LDSP + a_oc * 8] = *(const short8*)s1;
        }
        // stage B gate+up (fp32 -> bf16, transposed into LDS)
        {
            short8 g0, g1, u0, u1;
            #pragma unroll
            for (int j = 0; j < 8; j++) {
                size_t roff = (size_t)(k0 + b_ko * 8 + j) * ldb + n0 + b_n;
                float2 vg = *(const float2*)&Bg[roff];
                float2 vu = *(const float2*)&Bu[roff];
                g0[j] = (short)f2bf(vg.x); g1[j] = (short)f2bf(vg.y);
                u0[j] = (short)f2bf(vu.x); u1[j] = (short)f2bf(vu.y);
            }
            *(short8*)&Bgs[b_n * LDSP + b_ko * 8]       = g0;
            *(short8*)&Bgs[(b_n + 1) * LDSP + b_ko * 8] = g1;
            *(short8*)&Bus[b_n * LDSP + b_ko * 8]       = u0;
            *(short8*)&Bus[(b_n + 1) * LDSP + b_ko * 8] = u1;
        }
        __syncthreads();

        bf16x8 af[4], bg[4], bu[4];
        #pragma unroll
        for (int i = 0; i < 4; i++)
            af[i] = *(const bf16x8*)&Als[(wm + i * 16 + l15) * LDSP + quad * 8];
        #pragma unroll
        for (int j = 0; j < 4; j++) {
            bg[j] = *(const bf16x8*)&Bgs[(wn + j * 16 + l15) * LDSP + quad * 8];
            bu[j] = *(const bf16x8*)&Bus[(wn + j * 16 + l15) * LDSP + quad * 8];
        }
        #pragma unroll
        for (int i = 0; i < 4; i++)
            #pragma unroll
            for (int j = 0; j < 4; j++) {
                accg[i][j] = __builtin_amdgcn_mfma_f32_16x16x32_bf16(af[i], bg[j], accg[i][j], 0, 0, 0);
                accu[i][j] = __builtin_amdgcn_mfma_f32_16x16x32_bf16(af[i], bu[j], accu[i][j], 0, 0, 0);
            }
    }

    // epilogue: silu(g)*u*rowscale -> bf16
    #pragma unroll
    for (int i = 0; i < 4; i++) {
        #pragma unroll
        for (int r = 0; r < 4; r++) {
            int t = t0 + wm + i * 16 + quad * 4 + r;
            float sc = comb ? comb[(size_t)t * E_NUM + z] : 1.f;
            #pragma unroll
            for (int j = 0; j < 4; j++) {
                float g = accg[i][j][r], u = accu[i][j][r];
                float sg = g / (1.f + __expf(-g));
                float v = sg * u * sc;
                int c = n0 + wn + j * 16 + l15;
                C[(size_t)t * ldc + c] = f2bf(v);
            }
        }
    }
}

// ---------------- GEMM2: Out (+)= A @ B over nseg K-segments, fp32 out ----------------
// A: bf16 [nseg][M,Kper] (lda=Kper). B: fp32 [nseg][Kper,N] row-major, transpose-staged.
__global__ __launch_bounds__(256)
void gemm2_kernel(const ushort_t* __restrict__ A0, size_t aSeg, int lda,
                  const float* __restrict__ B0, size_t bSeg, int ldb,
                  float* __restrict__ Out, int N,
                  int nseg, int Kper, int accum)
{
    __shared__ ushort_t Als[BM * LDSP];
    __shared__ ushort_t Bls[BN * LDSP];

    int t0 = blockIdx.x * BM;
    int n0 = blockIdx.y * BN;
    int tid = threadIdx.x;
    int lane = tid & 63, wid = tid >> 6;
    int wm = (wid & 1) * 64, wn = (wid >> 1) * 64;
    int quad = lane >> 4, l15 = lane & 15;

    float4v acc[4][4];
    #pragma unroll
    for (int i = 0; i < 4; i++)
        #pragma unroll
        for (int j = 0; j < 4; j++) acc[i][j] = (float4v){0.f, 0.f, 0.f, 0.f};

    int a_r  = tid >> 2, a_oc = tid & 3;
    int b_ko = (tid >> 4) & 3;
    int b_n  = 2 * ((tid & 15) + ((tid >> 6) << 4));

    for (int seg = 0; seg < nseg; seg++) {
        const ushort_t* A = A0 + (size_t)seg * aSeg;
        const float*    B = B0 + (size_t)seg * bSeg;
        for (int k0 = 0; k0 < Kper; k0 += BK) {
            __syncthreads();
            {
                const ushort_t* s0 = A + (size_t)(t0 + a_r) * lda + k0 + a_oc * 8;
                *(short8*)&Als[a_r * LDSP + a_oc * 8] = *(const short8*)s0;
                const ushort_t* s1 = A + (size_t)(t0 + a_r + 64) * lda + k0 + a_oc * 8;
                *(short8*)&Als[(a_r + 64) * LDSP + a_oc * 8] = *(const short8*)s1;
            }
            {
                short8 r0, r1;
                #pragma unroll
                for (int j = 0; j < 8; j++) {
                    size_t roff = (size_t)(k0 + b_ko * 8 + j) * ldb + n0 + b_n;
                    float2 v = *(const float2*)&B[roff];
                    r0[j] = (short)f2bf(v.x); r1[j] = (short)f2bf(v.y);
                }
                *(short8*)&Bls[b_n * LDSP + b_ko * 8]       = r0;
                *(short8*)&Bls[(b_n + 1) * LDSP + b_ko * 8] = r1;
            }
            __syncthreads();

            bf16x8 af[4], bf[4];
            #pragma unroll
            for (int i = 0; i < 4; i++)
                af[i] = *(const bf16x8*)&Als[(wm + i * 16 + l15) * LDSP + quad * 8];
            #pragma unroll
            for (int j = 0; j < 4; j++)
                bf[j] = *(const bf16x8*)&Bls[(wn + j * 16 + l15) * LDSP + quad * 8];
            #pragma unroll
            for (int i = 0; i < 4; i++)
                #pragma unroll
                for (int j = 0; j < 4; j++)
                    acc[i][j] = __builtin_amdgcn_mfma_f32_16x16x32_bf16(af[i], bf[j], acc[i][j], 0, 0, 0);
        }
    }

    #pragma unroll
    for (int i = 0; i < 4; i++) {
        #pragma unroll
        for (int r = 0; r < 4; r++) {
            int t = t0 + wm + i * 16 + quad * 4 + r;
            #pragma unroll
            for (int j = 0; j < 4; j++) {
                int c = n0 + wn + j * 16 + l15;
                size_t idx = (size_t)t * N + c;
                float v = acc[i][j][r];
                if (accum) Out[idx] += v; else Out[idx] = v;
            }
        }
    }
}

extern "C" void kernel_launch(void* const* d_in, const int* in_sizes, int n_in,
                              void* d_out, int out_size, void* d_ws, size_t ws_size,
                              hipStream_t stream) {
    const float* h      = (const float*)d_in[0];
    const float* gate_w = (const float*)d_in[1];
    const float* Wg     = (const float*)d_in[2];
    const float* Wu     = (const float*)d_in[3];
    const float* Wd     = (const float*)d_in[4];
    const float* sWg    = (const float*)d_in[5];
    const float* sWu    = (const float*)d_in[6];
    const float* sWd    = (const float*)d_in[7];
    float* out = (float*)d_out;
    int T = in_sizes[0] / H_DIM;

    // workspace layout (~80.2 MiB total)
    char* ws = (char*)d_ws;
    size_t off = 0;
    ushort_t* h_bf = (ushort_t*)(ws + off); off += (size_t)T * H_DIM * sizeof(ushort_t);
    float* comb    = (float*)(ws + off);    off += (size_t)T * E_NUM * sizeof(float);
    off = (off + 255) & ~(size_t)255;
    ushort_t* act_s = (ushort_t*)(ws + off); off += (size_t)T * IS_DIM * sizeof(ushort_t);
    ushort_t* act_r = (ushort_t*)(ws + off); off += (size_t)E_NUM * T * IM_DIM * sizeof(ushort_t);
    (void)ws_size; (void)n_in; (void)out_size;

    int n4 = T * H_DIM / 4;
    cast_h_kernel<<<(n4 + 255) / 256, 256, 0, stream>>>(h, h_bf, n4);
    router_kernel<<<T, 64, 0, stream>>>(h, gate_w, comb, T);

    // shared expert gate/up: act_s = silu(h@sWg)*(h@sWu)   [T, IS]
    gemm1_kernel<<<dim3(T / BM, IS_DIM / BN, 1), 256, 0, stream>>>(
        h_bf, H_DIM, sWg, sWu, 0, IS_DIM, act_s, 0, IS_DIM, nullptr, H_DIM);

    // routed gate/up (dense over experts), scaled by comb: act_r[e] = comb[:,e]*silu(h@Wg_e)*(h@Wu_e)
    gemm1_kernel<<<dim3(T / BM, IM_DIM / BN, E_NUM), 256, 0, stream>>>(
        h_bf, H_DIM, Wg, Wu, (size_t)H_DIM * IM_DIM, IM_DIM,
        act_r, (size_t)T * IM_DIM, IM_DIM, comb, H_DIM);

    // shared down-proj: out = act_s @ sWd
    gemm2_kernel<<<dim3(T / BM, H_DIM / BN, 1), 256, 0, stream>>>(
        act_s, 0, IS_DIM, sWd, 0, H_DIM, out, H_DIM, 1, IS_DIM, 0);

    // routed down-proj + combine: out += sum_e act_r[e] @ Wd_e   (segmented K = 16*1024)
    gemm2_kernel<<<dim3(T / BM, H_DIM / BN, 1), 256, 0, stream>>>(
        act_r, (size_t)T * IM_DIM, IM_DIM, Wd, (size_t)IM_DIM * H_DIM, H_DIM,
        out, H_DIM, E_NUM, IM_DIM, 1);
}

// Round 2
// 1148.541 us; speedup vs baseline: 1.8059x; 1.8059x over previous
//
#include <hip/hip_runtime.h>
#include <hip/hip_bf16.h>
#include <stdint.h>

#define H_DIM  2048
#define IM_DIM 1024
#define E_NUM  16
#define TOPK   8
#define IS_DIM 2048
#define SCALE_F 2.5f

#define BM 128
#define BN 128
#define BK 32
#define LDSP 40   // fallback-path padded LDS row stride

typedef __attribute__((ext_vector_type(8))) short   short8;
typedef __attribute__((ext_vector_type(8))) __bf16  bf16x8;
typedef __attribute__((ext_vector_type(4))) float   float4v;
typedef unsigned short ushort_t;

// async global->LDS, 16B per lane; LDS dest = wave-uniform base + lane*16
#define GLOAD_LDS16(gp, lp) \
    __builtin_amdgcn_global_load_lds((__attribute__((address_space(1))) void*)(gp), \
                                     (__attribute__((address_space(3))) void*)(lp), 16, 0, 0)

static __device__ __forceinline__ ushort_t f2bf(float x) {
    union { float f; uint32_t u; } v; v.f = x;
    uint32_t r = v.u + 0x7fffu + ((v.u >> 16) & 1u);  // RNE
    return (ushort_t)(r >> 16);
}

// ---------------- cast h (fp32 -> bf16) ----------------
__global__ void cast_h_kernel(const float* __restrict__ h, ushort_t* __restrict__ hb, int n4) {
    int i = blockIdx.x * blockDim.x + threadIdx.x;
    if (i < n4) {
        float4 v = ((const float4*)h)[i];
        ushort4 o;
        o.x = f2bf(v.x); o.y = f2bf(v.y); o.z = f2bf(v.z); o.w = f2bf(v.w);
        ((ushort4*)hb)[i] = o;
    }
}

// ---------------- router: sigmoid + top-8 -> dense comb[T,E] ----------------
__global__ void router_kernel(const float* __restrict__ h, const float* __restrict__ gw,
                              float* __restrict__ comb, int T) {
    int t = blockIdx.x;
    int l = threadIdx.x;
    const float* hr = h + (size_t)t * H_DIM;
    __shared__ float logits[E_NUM];
    for (int e = 0; e < E_NUM; e++) {
        const float* g = gw + e * H_DIM;
        float p = 0.f;
        #pragma unroll 8
        for (int j = l; j < H_DIM; j += 64) p += hr[j] * g[j];
        #pragma unroll
        for (int off = 32; off > 0; off >>= 1) p += __shfl_down(p, off);
        if (l == 0) logits[e] = p;
    }
    __syncthreads();
    if (l == 0) {
        float sig[E_NUM]; bool sel[E_NUM];
        #pragma unroll
        for (int e = 0; e < E_NUM; e++) { sig[e] = 1.f / (1.f + expf(-logits[e])); sel[e] = false; }
        #pragma unroll
        for (int k = 0; k < TOPK; k++) {
            int bi = 0; float bv = -1.f;
            #pragma unroll
            for (int e = 0; e < E_NUM; e++)
                if (!sel[e] && sig[e] > bv) { bv = sig[e]; bi = e; }
            sel[bi] = true;
        }
        float s = 0.f;
        #pragma unroll
        for (int e = 0; e < E_NUM; e++) if (sel[e]) s += sig[e];
        float inv = SCALE_F / (s + 1e-6f);
        #pragma unroll
        for (int e = 0; e < E_NUM; e++)
            comb[(size_t)t * E_NUM + e] = sel[e] ? sig[e] * inv : 0.f;
    }
}

// ---------------- transpose+convert: fp32 [z][K][N] -> bf16 [z][N][K] ----------------
__global__ __launch_bounds__(256)
void transpose_cvt_kernel(const float* __restrict__ src, ushort_t* __restrict__ dst,
                          int K, int N, size_t sStride, size_t dStride)
{
    __shared__ float tile[64 * 65];
    int z = blockIdx.z;
    const float* S = src + (size_t)z * sStride;
    ushort_t* D = dst + (size_t)z * dStride;
    int k0 = blockIdx.x * 64, n0 = blockIdx.y * 64;
    int tid = threadIdx.x;
    int tr = tid >> 4, tc = (tid & 15) * 4;
    #pragma unroll
    for (int p = 0; p < 4; p++) {
        int r = tr + 16 * p;
        float4 v = *(const float4*)&S[(size_t)(k0 + r) * N + n0 + tc];
        tile[(tc + 0) * 65 + r] = v.x;
        tile[(tc + 1) * 65 + r] = v.y;
        tile[(tc + 2) * 65 + r] = v.z;
        tile[(tc + 3) * 65 + r] = v.w;
    }
    __syncthreads();
    #pragma unroll
    for (int p = 0; p < 4; p++) {
        int n = tr + 16 * p;
        ushort4 o;
        o.x = f2bf(tile[n * 65 + tc + 0]);
        o.y = f2bf(tile[n * 65 + tc + 1]);
        o.z = f2bf(tile[n * 65 + tc + 2]);
        o.w = f2bf(tile[n * 65 + tc + 3]);
        *(ushort4*)&D[(size_t)(n0 + n) * K + k0 + tc] = o;
    }
}

// ================= FAST PATH: m97-style GEMMs, B pre-transposed bf16 [N,K] ============

// GEMM1: C = rowscale * silu(A@Bg^T) * (A@Bu^T), bf16 out
__global__ __launch_bounds__(256, 2)
void gemm1f_kernel(const ushort_t* __restrict__ A, int lda,
                   const ushort_t* __restrict__ Bg0, const ushort_t* __restrict__ Bu0,
                   size_t bSeg,
                   ushort_t* __restrict__ C0, size_t cSeg, int ldc,
                   const float* __restrict__ comb, int Kdim)
{
    __shared__ ushort_t Als[BM * BK];
    __shared__ ushort_t Bgs[BN * BK];
    __shared__ ushort_t Bus[BN * BK];

    int z = blockIdx.z;
    const ushort_t* Bg = Bg0 + (size_t)z * bSeg;
    const ushort_t* Bu = Bu0 + (size_t)z * bSeg;
    ushort_t* C = C0 + (size_t)z * cSeg;
    int t0 = blockIdx.x * BM, n0 = blockIdx.y * BN;
    int tid = threadIdx.x, lane = tid & 63, wid = tid >> 6;
    int wm = (wid & 1) * 64, wn = (wid >> 1) * 64;
    int quad = lane >> 4, l15 = lane & 15;

    int srow = lane >> 2;          // 0..15
    int scol = (lane & 3) * 8;     // element col (16B granules)
    int rb = wid * 32;             // wave's 32-row slab

    float4v accg[4][4], accu[4][4];
    #pragma unroll
    for (int i = 0; i < 4; i++)
        #pragma unroll
        for (int j = 0; j < 4; j++) {
            accg[i][j] = (float4v){0.f, 0.f, 0.f, 0.f};
            accu[i][j] = (float4v){0.f, 0.f, 0.f, 0.f};
        }

    const ushort_t* Ab0  = A  + (size_t)(t0 + rb + srow)      * lda  + scol;
    const ushort_t* Ab1  = A  + (size_t)(t0 + rb + 16 + srow) * lda  + scol;
    const ushort_t* Bgb0 = Bg + (size_t)(n0 + rb + srow)      * Kdim + scol;
    const ushort_t* Bgb1 = Bg + (size_t)(n0 + rb + 16 + srow) * Kdim + scol;
    const ushort_t* Bub0 = Bu + (size_t)(n0 + rb + srow)      * Kdim + scol;
    const ushort_t* Bub1 = Bu + (size_t)(n0 + rb + 16 + srow) * Kdim + scol;
    ushort_t* lA0  = &Als[rb * BK];
    ushort_t* lA1  = &Als[(rb + 16) * BK];
    ushort_t* lBg0 = &Bgs[rb * BK];
    ushort_t* lBg1 = &Bgs[(rb + 16) * BK];
    ushort_t* lBu0 = &Bus[rb * BK];
    ushort_t* lBu1 = &Bus[(rb + 16) * BK];

    for (int k0 = 0; k0 < Kdim; k0 += BK) {
        GLOAD_LDS16(Ab0 + k0,  lA0);
        GLOAD_LDS16(Ab1 + k0,  lA1);
        GLOAD_LDS16(Bgb0 + k0, lBg0);
        GLOAD_LDS16(Bgb1 + k0, lBg1);
        GLOAD_LDS16(Bub0 + k0, lBu0);
        GLOAD_LDS16(Bub1 + k0, lBu1);
        __syncthreads();

        bf16x8 af[4], bg[4], bu[4];
        #pragma unroll
        for (int i = 0; i < 4; i++)
            af[i] = *(const bf16x8*)&Als[(wm + i * 16 + l15) * BK + quad * 8];
        #pragma unroll
        for (int j = 0; j < 4; j++) {
            bg[j] = *(const bf16x8*)&Bgs[(wn + j * 16 + l15) * BK + quad * 8];
            bu[j] = *(const bf16x8*)&Bus[(wn + j * 16 + l15) * BK + quad * 8];
        }
        #pragma unroll
        for (int i = 0; i < 4; i++)
            #pragma unroll
            for (int j = 0; j < 4; j++) {
                accg[i][j] = __builtin_amdgcn_mfma_f32_16x16x32_bf16(af[i], bg[j], accg[i][j], 0, 0, 0);
                accu[i][j] = __builtin_amdgcn_mfma_f32_16x16x32_bf16(af[i], bu[j], accu[i][j], 0, 0, 0);
            }
        __syncthreads();
    }

    #pragma unroll
    for (int i = 0; i < 4; i++) {
        #pragma unroll
        for (int r = 0; r < 4; r++) {
            int t = t0 + wm + i * 16 + quad * 4 + r;
            float sc = comb ? comb[(size_t)t * E_NUM + z] : 1.f;
            #pragma unroll
            for (int j = 0; j < 4; j++) {
                float g = accg[i][j][r], u = accu[i][j][r];
                float sg = g / (1.f + __expf(-g));
                float v = sg * u * sc;
                int c = n0 + wn + j * 16 + l15;
                C[(size_t)t * ldc + c] = f2bf(v);
            }
        }
    }
}

// GEMM2: Out (=|+=|atomic+=) sum_seg A_seg @ B_seg^T, fp32 out
__global__ __launch_bounds__(256, 2)
void gemm2f_kernel(const ushort_t* __restrict__ A0, size_t aSeg, int lda,
                   const ushort_t* __restrict__ B0, size_t bSeg,
                   float* __restrict__ Out, int N,
                   int nsegPerZ, int Kper, int mode)
{
    __shared__ ushort_t Als[BM * BK];
    __shared__ ushort_t Bls[BN * BK];

    int t0 = blockIdx.x * BM, n0 = blockIdx.y * BN;
    int z = blockIdx.z;
    int tid = threadIdx.x, lane = tid & 63, wid = tid >> 6;
    int wm = (wid & 1) * 64, wn = (wid >> 1) * 64;
    int quad = lane >> 4, l15 = lane & 15;

    int srow = lane >> 2;
    int scol = (lane & 3) * 8;
    int rb = wid * 32;

    float4v acc[4][4];
    #pragma unroll
    for (int i = 0; i < 4; i++)
        #pragma unroll
        for (int j = 0; j < 4; j++) acc[i][j] = (float4v){0.f, 0.f, 0.f, 0.f};

    ushort_t* lA0 = &Als[rb * BK];
    ushort_t* lA1 = &Als[(rb + 16) * BK];
    ushort_t* lB0 = &Bls[rb * BK];
    ushort_t* lB1 = &Bls[(rb + 16) * BK];

    for (int s = 0; s < nsegPerZ; s++) {
        int seg = z * nsegPerZ + s;
        const ushort_t* A = A0 + (size_t)seg * aSeg;
        const ushort_t* B = B0 + (size_t)seg * bSeg;
        const ushort_t* Ab0 = A + (size_t)(t0 + rb + srow)      * lda  + scol;
        const ushort_t* Ab1 = A + (size_t)(t0 + rb + 16 + srow) * lda  + scol;
        const ushort_t* Bb0 = B + (size_t)(n0 + rb + srow)      * Kper + scol;
        const ushort_t* Bb1 = B + (size_t)(n0 + rb + 16 + srow) * Kper + scol;

        for (int k0 = 0; k0 < Kper; k0 += BK) {
            GLOAD_LDS16(Ab0 + k0, lA0);
            GLOAD_LDS16(Ab1 + k0, lA1);
            GLOAD_LDS16(Bb0 + k0, lB0);
            GLOAD_LDS16(Bb1 + k0, lB1);
            __syncthreads();

            bf16x8 af[4], bf[4];
            #pragma unroll
            for (int i = 0; i < 4; i++)
                af[i] = *(const bf16x8*)&Als[(wm + i * 16 + l15) * BK + quad * 8];
            #pragma unroll
            for (int j = 0; j < 4; j++)
                bf[j] = *(const bf16x8*)&Bls[(wn + j * 16 + l15) * BK + quad * 8];
            #pragma unroll
            for (int i = 0; i < 4; i++)
                #pragma unroll
                for (int j = 0; j < 4; j++)
                    acc[i][j] = __builtin_amdgcn_mfma_f32_16x16x32_bf16(af[i], bf[j], acc[i][j], 0, 0, 0);
            __syncthreads();
        }
    }

    #pragma unroll
    for (int i = 0; i < 4; i++) {
        #pragma unroll
        for (int r = 0; r < 4; r++) {
            int t = t0 + wm + i * 16 + quad * 4 + r;
            #pragma unroll
            for (int j = 0; j < 4; j++) {
                int c = n0 + wn + j * 16 + l15;
                size_t idx = (size_t)t * N + c;
                float v = acc[i][j][r];
                if (mode == 0) Out[idx] = v;
                else if (mode == 1) Out[idx] += v;
                else atomicAdd(&Out[idx], v);
            }
        }
    }
}

// ================= FALLBACK PATH (round-1 kernels, ws-lean) ==========================

__global__ __launch_bounds__(256)
void gemm1_kernel(const ushort_t* __restrict__ A, int lda,
                  const float* __restrict__ Bg0, const float* __restrict__ Bu0,
                  size_t bSeg, int ldb,
                  ushort_t* __restrict__ C0, size_t cSeg, int ldc,
                  const float* __restrict__ comb, int Kdim)
{
    __shared__ ushort_t Als[BM * LDSP];
    __shared__ ushort_t Bgs[BN * LDSP];
    __shared__ ushort_t Bus[BN * LDSP];

    int z = blockIdx.z;
    const float* Bg = Bg0 + (size_t)z * bSeg;
    const float* Bu = Bu0 + (size_t)z * bSeg;
    ushort_t* C = C0 + (size_t)z * cSeg;

    int t0 = blockIdx.x * BM;
    int n0 = blockIdx.y * BN;
    int tid = threadIdx.x;
    int lane = tid & 63, wid = tid >> 6;
    int wm = (wid & 1) * 64, wn = (wid >> 1) * 64;
    int quad = lane >> 4, l15 = lane & 15;

    float4v accg[4][4], accu[4][4];
    #pragma unroll
    for (int i = 0; i < 4; i++)
        #pragma unroll
        for (int j = 0; j < 4; j++) {
            accg[i][j] = (float4v){0.f, 0.f, 0.f, 0.f};
            accu[i][j] = (float4v){0.f, 0.f, 0.f, 0.f};
        }

    int a_r  = tid >> 2, a_oc = tid & 3;
    int b_ko = (tid >> 4) & 3;
    int b_n  = 2 * ((tid & 15) + ((tid >> 6) << 4));

    for (int k0 = 0; k0 < Kdim; k0 += BK) {
        __syncthreads();
        {
            const ushort_t* s0 = A + (size_t)(t0 + a_r) * lda + k0 + a_oc * 8;
            *(short8*)&Als[a_r * LDSP + a_oc * 8] = *(const short8*)s0;
            const ushort_t* s1 = A + (size_t)(t0 + a_r + 64) * lda + k0 + a_oc * 8;
            *(short8*)&Als[(a_r + 64) * LDSP + a_oc * 8] = *(const short8*)s1;
        }
        {
            short8 g0, g1, u0, u1;
            #pragma unroll
            for (int j = 0; j < 8; j++) {
                size_t roff = (size_t)(k0 + b_ko * 8 + j) * ldb + n0 + b_n;
                float2 vg = *(const float2*)&Bg[roff];
                float2 vu = *(const float2*)&Bu[roff];
                g0[j] = (short)f2bf(vg.x); g1[j] = (short)f2bf(vg.y);
                u0[j] = (short)f2bf(vu.x); u1[j] = (short)f2bf(vu.y);
            }
            *(short8*)&Bgs[b_n * LDSP + b_ko * 8]       = g0;
            *(short8*)&Bgs[(b_n + 1) * LDSP + b_ko * 8] = g1;
            *(short8*)&Bus[b_n * LDSP + b_ko * 8]       = u0;
            *(short8*)&Bus[(b_n + 1) * LDSP + b_ko * 8] = u1;
        }
        __syncthreads();

        bf16x8 af[4], bg[4], bu[4];
        #pragma unroll
        for (int i = 0; i < 4; i++)
            af[i] = *(const bf16x8*)&Als[(wm + i * 16 + l15) * LDSP + quad * 8];
        #pragma unroll
        for (int j = 0; j < 4; j++) {
            bg[j] = *(const bf16x8*)&Bgs[(wn + j * 16 + l15) * LDSP + quad * 8];
            bu[j] = *(const bf16x8*)&Bus[(wn + j * 16 + l15) * LDSP + quad * 8];
        }
        #pragma unroll
        for (int i = 0; i < 4; i++)
            #pragma unroll
            for (int j = 0; j < 4; j++) {
                accg[i][j] = __builtin_amdgcn_mfma_f32_16x16x32_bf16(af[i], bg[j], accg[i][j], 0, 0, 0);
                accu[i][j] = __builtin_amdgcn_mfma_f32_16x16x32_bf16(af[i], bu[j], accu[i][j], 0, 0, 0);
            }
    }

    #pragma unroll
    for (int i = 0; i < 4; i++) {
        #pragma unroll
        for (int r = 0; r < 4; r++) {
            int t = t0 + wm + i * 16 + quad * 4 + r;
            float sc = comb ? comb[(size_t)t * E_NUM + z] : 1.f;
            #pragma unroll
            for (int j = 0; j < 4; j++) {
                float g = accg[i][j][r], u = accu[i][j][r];
                float sg = g / (1.f + __expf(-g));
                float v = sg * u * sc;
                int c = n0 + wn + j * 16 + l15;
                C[(size_t)t * ldc + c] = f2bf(v);
            }
        }
    }
}

__global__ __launch_bounds__(256)
void gemm2_kernel(const ushort_t* __restrict__ A0, size_t aSeg, int lda,
                  const float* __restrict__ B0, size_t bSeg, int ldb,
                  float* __restrict__ Out, int N,
                  int nseg, int Kper, int accum)
{
    __shared__ ushort_t Als[BM * LDSP];
    __shared__ ushort_t Bls[BN * LDSP];

    int t0 = blockIdx.x * BM;
    int n0 = blockIdx.y * BN;
    int tid = threadIdx.x;
    int lane = tid & 63, wid = tid >> 6;
    int wm = (wid & 1) * 64, wn = (wid >> 1) * 64;
    int quad = lane >> 4, l15 = lane & 15;

    float4v acc[4][4];
    #pragma unroll
    for (int i = 0; i < 4; i++)
        #pragma unroll
        for (int j = 0; j < 4; j++) acc[i][j] = (float4v){0.f, 0.f, 0.f, 0.f};

    int a_r  = tid >> 2, a_oc = tid & 3;
    int b_ko = (tid >> 4) & 3;
    int b_n  = 2 * ((tid & 15) + ((tid >> 6) << 4));

    for (int seg = 0; seg < nseg; seg++) {
        const ushort_t* A = A0 + (size_t)seg * aSeg;
        const float*    B = B0 + (size_t)seg * bSeg;
        for (int k0 = 0; k0 < Kper; k0 += BK) {
            __syncthreads();
            {
                const ushort_t* s0 = A + (size_t)(t0 + a_r) * lda + k0 + a_oc * 8;
                *(short8*)&Als[a_r * LDSP + a_oc * 8] = *(const short8*)s0;
                const ushort_t* s1 = A + (size_t)(t0 + a_r + 64) * lda + k0 + a_oc * 8;
                *(short8*)&Als[(a_r + 64) * LDSP + a_oc * 8] = *(const short8*)s1;
            }
            {
                short8 r0, r1;
                #pragma unroll
                for (int j = 0; j < 8; j++) {
                    size_t roff = (size_t)(k0 + b_ko * 8 + j) * ldb + n0 + b_n;
                    float2 v = *(const float2*)&B[roff];
                    r0[j] = (short)f2bf(v.x); r1[j] = (short)f2bf(v.y);
                }
                *(short8*)&Bls[b_n * LDSP + b_ko * 8]       = r0;
                *(short8*)&Bls[(b_n + 1) * LDSP + b_ko * 8] = r1;
            }
            __syncthreads();

            bf16x8 af[4], bf[4];
            #pragma unroll
            for (int i = 0; i < 4; i++)
                af[i] = *(const bf16x8*)&Als[(wm + i * 16 + l15) * LDSP + quad * 8];
            #pragma unroll
            for (int j = 0; j < 4; j++)
                bf[j] = *(const bf16x8*)&Bls[(wn + j * 16 + l15) * LDSP + quad * 8];
            #pragma unroll
            for (int i = 0; i < 4; i++)
                #pragma unroll
                for (int j = 0; j < 4; j++)
                    acc[i][j] = __builtin_amdgcn_mfma_f32_16x16x32_bf16(af[i], bf[j], acc[i][j], 0, 0, 0);
        }
    }

    #pragma unroll
    for (int i = 0; i < 4; i++) {
        #pragma unroll
        for (int r = 0; r < 4; r++) {
            int t = t0 + wm + i * 16 + quad * 4 + r;
            #pragma unroll
            for (int j = 0; j < 4; j++) {
                int c = n0 + wn + j * 16 + l15;
                size_t idx = (size_t)t * N + c;
                float v = acc[i][j][r];
                if (accum) Out[idx] += v; else Out[idx] = v;
            }
        }
    }
}

// =====================================================================================

extern "C" void kernel_launch(void* const* d_in, const int* in_sizes, int n_in,
                              void* d_out, int out_size, void* d_ws, size_t ws_size,
                              hipStream_t stream) {
    const float* h      = (const float*)d_in[0];
    const float* gate_w = (const float*)d_in[1];
    const float* Wg     = (const float*)d_in[2];
    const float* Wu     = (const float*)d_in[3];
    const float* Wd     = (const float*)d_in[4];
    const float* sWg    = (const float*)d_in[5];
    const float* sWu    = (const float*)d_in[6];
    const float* sWd    = (const float*)d_in[7];
    float* out = (float*)d_out;
    int T = in_sizes[0] / H_DIM;
    (void)n_in; (void)out_size;

    char* ws = (char*)d_ws;
    size_t off = 0;
    auto alloc = [&](size_t bytes) -> void* {
        void* p = ws + off;
        off = (off + bytes + 255) & ~(size_t)255;
        return p;
    };
    ushort_t* h_bf  = (ushort_t*)alloc((size_t)T * H_DIM * 2);
    float*    comb  = (float*)   alloc((size_t)T * E_NUM * 4);
    ushort_t* act_s = (ushort_t*)alloc((size_t)T * IS_DIM * 2);
    ushort_t* act_r = (ushort_t*)alloc((size_t)E_NUM * T * IM_DIM * 2);
    // fast-path weight buffers (reused over launch sequence)
    ushort_t* bufS1 = (ushort_t*)alloc((size_t)IS_DIM * H_DIM * 2);          // 8 MB
    ushort_t* bufS2 = (ushort_t*)alloc((size_t)IS_DIM * H_DIM * 2);          // 8 MB
    ushort_t* bufW1 = (ushort_t*)alloc((size_t)E_NUM * IM_DIM * H_DIM * 2);  // 64 MB
    ushort_t* bufW2 = (ushort_t*)alloc((size_t)E_NUM * IM_DIM * H_DIM * 2);  // 64 MB
    size_t need = off;

    int n4 = T * H_DIM / 4;
    cast_h_kernel<<<(n4 + 255) / 256, 256, 0, stream>>>(h, h_bf, n4);
    router_kernel<<<T, 64, 0, stream>>>(h, gate_w, comb, T);

    if (ws_size >= need) {
        // ---- fast path: pre-transposed bf16 weights + global_load_lds GEMMs ----
        // shared gate/up weights: [H][IS] -> [IS][H]
        transpose_cvt_kernel<<<dim3(H_DIM / 64, IS_DIM / 64, 1), 256, 0, stream>>>(
            sWg, bufS1, H_DIM, IS_DIM, 0, 0);
        transpose_cvt_kernel<<<dim3(H_DIM / 64, IS_DIM / 64, 1), 256, 0, stream>>>(
            sWu, bufS2, H_DIM, IS_DIM, 0, 0);
        gemm1f_kernel<<<dim3(T / BM, IS_DIM / BN, 1), 256, 0, stream>>>(
            h_bf, H_DIM, bufS1, bufS2, 0, act_s, 0, IS_DIM, nullptr, H_DIM);

        // routed gate/up weights: [E][H][IM] -> [E][IM][H]
        transpose_cvt_kernel<<<dim3(H_DIM / 64, IM_DIM / 64, E_NUM), 256, 0, stream>>>(
            Wg, bufW1, H_DIM, IM_DIM, (size_t)H_DIM * IM_DIM, (size_t)IM_DIM * H_DIM);
        transpose_cvt_kernel<<<dim3(H_DIM / 64, IM_DIM / 64, E_NUM), 256, 0, stream>>>(
            Wu, bufW2, H_DIM, IM_DIM, (size_t)H_DIM * IM_DIM, (size_t)IM_DIM * H_DIM);
        gemm1f_kernel<<<dim3(T / BM, IM_DIM / BN, E_NUM), 256, 0, stream>>>(
            h_bf, H_DIM, bufW1, bufW2, (size_t)IM_DIM * H_DIM,
            act_r, (size_t)T * IM_DIM, IM_DIM, comb, H_DIM);

        // shared down weight: [IS][H] -> [H][IS]  (reuse bufS1 after gemm1f shared)
        transpose_cvt_kernel<<<dim3(IS_DIM / 64, H_DIM / 64, 1), 256, 0, stream>>>(
            sWd, bufS1, IS_DIM, H_DIM, 0, 0);
        gemm2f_kernel<<<dim3(T / BM, H_DIM / BN, 1), 256, 0, stream>>>(
            act_s, 0, IS_DIM, bufS1, 0, out, H_DIM, 1, IS_DIM, 0);

        // routed down weight: [E][IM][H] -> [E][H][IM]  (reuse bufW1 after gemm1f routed)
        transpose_cvt_kernel<<<dim3(IM_DIM / 64, H_DIM / 64, E_NUM), 256, 0, stream>>>(
            Wd, bufW1, IM_DIM, H_DIM, (size_t)IM_DIM * H_DIM, (size_t)H_DIM * IM_DIM);
        gemm2f_kernel<<<dim3(T / BM, H_DIM / BN, 2), 256, 0, stream>>>(
            act_r, (size_t)T * IM_DIM, IM_DIM, bufW1, (size_t)H_DIM * IM_DIM,
            out, H_DIM, E_NUM / 2, IM_DIM, 2);
    } else {
        // ---- fallback: round-1 path (~80 MB ws) ----
        gemm1_kernel<<<dim3(T / BM, IS_DIM / BN, 1), 256, 0, stream>>>(
            h_bf, H_DIM, sWg, sWu, 0, IS_DIM, act_s, 0, IS_DIM, nullptr, H_DIM);
        gemm1_kernel<<<dim3(T / BM, IM_DIM / BN, E_NUM), 256, 0, stream>>>(
            h_bf, H_DIM, Wg, Wu, (size_t)H_DIM * IM_DIM, IM_DIM,
            act_r, (size_t)T * IM_DIM, IM_DIM, comb, H_DIM);
        gemm2_kernel<<<dim3(T / BM, H_DIM / BN, 1), 256, 0, stream>>>(
            act_s, 0, IS_DIM, sWd, 0, H_DIM, out, H_DIM, 1, IS_DIM, 0);
        gemm2_kernel<<<dim3(T / BM, H_DIM / BN, 1), 256, 0, stream>>>(
            act_r, (size_t)T * IM_DIM, IM_DIM, Wd, (size_t)IM_DIM * H_DIM, H_DIM,
            out, H_DIM, E_NUM, IM_DIM, 1);
    }
}